// Round 6
// baseline (102.423 us; speedup 1.0000x reference)
//
#include <hip/hip_runtime.h>
#include <hip/hip_bf16.h>

typedef int  int4v  __attribute__((ext_vector_type(4)));
typedef char char2v __attribute__((ext_vector_type(2)));

#define NROWS 8192
#define DIM 512
#define ROWB 512           // DIM * 1 byte (i8)
#define NT 4               // DIM / BK, BK = 128 (i8 elems) = 128 B rows

#define AS1(p) ((const __attribute__((address_space(1))) void*)(p))
#define AS3(p) ((__attribute__((address_space(3))) void*)(p))

#if __has_builtin(__builtin_amdgcn_exp2f)
#define EXP2(x) __builtin_amdgcn_exp2f(x)
#else
#define EXP2(x) exp2f(x)
#endif

// ---------------------------------------------------------------------------
// Kernel 1: per-row L2 normalize, i8 quantize (per-row symmetric scale),
// per-row diag dot (fp32, exact), zero rowsum.
//   q_i = round(127 * x_i / max|x|);  xn_i ~= q_i * s_row,  s_row = max|x|*rv/127
// ---------------------------------------------------------------------------
__global__ __launch_bounds__(256) void prep_kernel(
    const float* __restrict__ v, const float* __restrict__ u,
    char* __restrict__ vq, char* __restrict__ uq,
    float* __restrict__ sa, float* __restrict__ sb,
    float* __restrict__ diag, float* __restrict__ rowsum)
{
    const int row = blockIdx.x;
    const int t = threadIdx.x;
    const float2 a = reinterpret_cast<const float2*>(v + (size_t)row * DIM)[t];
    const float2 b = reinterpret_cast<const float2*>(u + (size_t)row * DIM)[t];
    float sv = a.x * a.x + a.y * a.y;
    float su = b.x * b.x + b.y * b.y;
    float sd = a.x * b.x + a.y * b.y;
    float mv = fmaxf(fabsf(a.x), fabsf(a.y));
    float mu = fmaxf(fabsf(b.x), fabsf(b.y));
#pragma unroll
    for (int m = 32; m; m >>= 1) {
        sv += __shfl_xor(sv, m);
        su += __shfl_xor(su, m);
        sd += __shfl_xor(sd, m);
        mv = fmaxf(mv, __shfl_xor(mv, m));
        mu = fmaxf(mu, __shfl_xor(mu, m));
    }
    __shared__ float red[5][4];
    const int wave = t >> 6;
    if ((t & 63) == 0) {
        red[0][wave] = sv; red[1][wave] = su; red[2][wave] = sd;
        red[3][wave] = mv; red[4][wave] = mu;
    }
    __syncthreads();
    sv = red[0][0] + red[0][1] + red[0][2] + red[0][3];
    su = red[1][0] + red[1][1] + red[1][2] + red[1][3];
    sd = red[2][0] + red[2][1] + red[2][2] + red[2][3];
    mv = fmaxf(fmaxf(red[3][0], red[3][1]), fmaxf(red[3][2], red[3][3]));
    mu = fmaxf(fmaxf(red[4][0], red[4][1]), fmaxf(red[4][2], red[4][3]));
    const float rv = 1.0f / fmaxf(sqrtf(sv), 1e-8f);
    const float ru = 1.0f / fmaxf(sqrtf(su), 1e-8f);
    const float qv = 127.0f / fmaxf(mv, 1e-20f);   // quantizer (rv cancels)
    const float qu = 127.0f / fmaxf(mu, 1e-20f);
    char2v cv, cu;
    cv[0] = (char)__float2int_rn(a.x * qv);
    cv[1] = (char)__float2int_rn(a.y * qv);
    cu[0] = (char)__float2int_rn(b.x * qu);
    cu[1] = (char)__float2int_rn(b.y * qu);
    *reinterpret_cast<char2v*>(vq + (size_t)row * DIM + 2 * t) = cv;
    *reinterpret_cast<char2v*>(uq + (size_t)row * DIM + 2 * t) = cu;
    if (t == 0) {
        sa[row] = mv * rv / 127.0f;    // dequant scale incl. normalization
        sb[row] = mu * ru / 127.0f;
        diag[row] = sd * rv * ru;      // exact fp32 cosine
        rowsum[row] = 0.0f;
    }
}

// ---------------------------------------------------------------------------
// Kernel 2: i8 version of the R5-proven 2-barrier 128x128 structure.
// BK=128 i8 (128-B LDS rows — byte-identical geometry to R5's bf16 BK=64),
// NT=4 K-tiles, XOR swizzle (0-conflict verified), 4 waves x 64x64.
// mfma_i32_16x16x64_i8: 16 B/lane contiguous K-chunk, same addressing as
// bf16 16x16x32; C/D layout dtype-independent [m121-m128].
// Epilogue: sim = iacc * sa_i * sb_j; rowsum += exp2(sim * 2*log2e).
// ---------------------------------------------------------------------------
__global__ __launch_bounds__(256, 2) void simsum_kernel(
    const char* __restrict__ A, const char* __restrict__ Bm,
    const float* __restrict__ sa, const float* __restrict__ sb,
    float* __restrict__ rowsum)
{
    __shared__ __align__(16) char lds[32768];   // A 16 KB | B 16 KB
    const int tid  = threadIdx.x;
    const int wave = tid >> 6;
    const int lane = tid & 63;
    const int ln15 = lane & 15;
    const int lhi  = lane >> 4;
    const int swz  = (ln15 & 7) << 4;          // read-side XOR (= row&7 <<4)

    const int brow = blockIdx.x, bcol = blockIdx.y;
    const int wr = wave >> 1, wc = wave & 1;   // 2x2 waves, 64x64 each

    const char* gA = A;
    const char* gB = Bm;
    const int growA = brow * 128;
    const int growB = bcol * 128;

    // staging: gload g covers LDS bytes [g*4096 + tid*16]; source column
    // chunk pre-swizzled so the swizzled read is the inverse (G21).
    const int r0   = tid >> 3;                  // row within 32-row group
    const int sl16 = (((tid & 7) ^ ((tid >> 3) & 7)) << 4);

    int4v acc[4][4];
#pragma unroll
    for (int m = 0; m < 4; ++m)
#pragma unroll
        for (int n = 0; n < 4; ++n)
            acc[m][n] = (int4v){0, 0, 0, 0};

    for (int t = 0; t < NT; ++t) {
#pragma unroll
        for (int g = 0; g < 4; ++g) {
            const int row = g * 32 + r0;
            __builtin_amdgcn_global_load_lds(
                AS1(gA + (size_t)(growA + row) * ROWB + t * 128 + sl16),
                AS3(lds + g * 4096 + tid * 16), 16, 0, 0);
        }
#pragma unroll
        for (int g = 0; g < 4; ++g) {
            const int row = g * 32 + r0;
            __builtin_amdgcn_global_load_lds(
                AS1(gB + (size_t)(growB + row) * ROWB + t * 128 + sl16),
                AS3(lds + 16384 + g * 4096 + tid * 16), 16, 0, 0);
        }
        __syncthreads();   // drains vmcnt (staging done) + lgkmcnt

#pragma unroll
        for (int kk = 0; kk < 2; ++kk) {
            int4v Af[4], Bf[4];
#pragma unroll
            for (int m = 0; m < 4; ++m) {
                const int r = wr * 64 + m * 16 + ln15;
                Af[m] = *(const int4v*)(lds + r * 128 +
                                        ((kk * 64 + lhi * 16) ^ swz));
            }
#pragma unroll
            for (int n = 0; n < 4; ++n) {
                const int r = wc * 64 + n * 16 + ln15;
                Bf[n] = *(const int4v*)(lds + 16384 + r * 128 +
                                        ((kk * 64 + lhi * 16) ^ swz));
            }
#pragma unroll
            for (int m = 0; m < 4; ++m)
#pragma unroll
                for (int n = 0; n < 4; ++n)
                    acc[m][n] = __builtin_amdgcn_mfma_i32_16x16x64_i8(
                        Af[m], Bf[n], acc[m][n], 0, 0, 0);
        }
        __syncthreads();   // all reads done before next stage overwrites
    }

    // ---- epilogue: rowsum += sum over this block's 128 cols of exp(2*sim)
    // C/D layout: col = lane&15, row = (lane>>4)*4 + reg  [m89/m91 verified]
    const float C2 = 2.885390081777927f;   // 2 * log2(e)
    float sbv[4];
#pragma unroll
    for (int n = 0; n < 4; ++n)
        sbv[n] = sb[growB + wc * 64 + n * 16 + ln15];
#pragma unroll
    for (int m = 0; m < 4; ++m) {
#pragma unroll
        for (int rr = 0; rr < 4; ++rr) {
            const int grow = growA + wr * 64 + m * 16 + lhi * 4 + rr;
            const float g = sa[grow] * C2;
            float s = 0.f;
#pragma unroll
            for (int n = 0; n < 4; ++n)
                s += EXP2((float)acc[m][n][rr] * g * sbv[n]);
            s += __shfl_xor(s, 1);
            s += __shfl_xor(s, 2);
            s += __shfl_xor(s, 4);
            s += __shfl_xor(s, 8);
            if (ln15 == 0)
                atomicAdd(&rowsum[grow], s);
        }
    }
}

// ---------------------------------------------------------------------------
// Kernel 3: loss_i = log(exp(2*diag_i) + rowsum_i) - 2*diag_i
// ---------------------------------------------------------------------------
__global__ __launch_bounds__(256) void loss_kernel(
    const float* __restrict__ diag, const float* __restrict__ rowsum,
    float* __restrict__ out)
{
    const int i = blockIdx.x * 256 + threadIdx.x;
    const float d2 = diag[i] * 2.0f;
    out[i] = logf(expf(d2) + rowsum[i]) - d2;
}

extern "C" void kernel_launch(void* const* d_in, const int* in_sizes, int n_in,
                              void* d_out, int out_size, void* d_ws, size_t ws_size,
                              hipStream_t stream) {
    const float* v = (const float*)d_in[0];
    const float* u = (const float*)d_in[1];
    float* out = (float*)d_out;
    char* ws = (char*)d_ws;
    char*  vq     = ws;                                   // 4 MiB
    char*  uq     = ws + (size_t)4194304;                 // 4 MiB
    float* sa     = (float*)(ws + (size_t)8388608);       // 32 KiB
    float* sb     = (float*)(ws + (size_t)8388608 + 32768);
    float* diag   = (float*)(ws + (size_t)8388608 + 65536);
    float* rowsum = (float*)(ws + (size_t)8388608 + 98304);

    prep_kernel<<<NROWS, 256, 0, stream>>>(v, u, vq, uq, sa, sb, diag, rowsum);
    dim3 grid(64, 64);
    simsum_kernel<<<grid, 256, 0, stream>>>(vq, uq, sa, sb, rowsum);
    loss_kernel<<<NROWS / 256, 256, 0, stream>>>(diag, rowsum, out);
}

// Round 7
// 53.186 us; speedup vs baseline: 1.9257x; 1.9257x over previous
//
#include <hip/hip_runtime.h>

typedef int   int4v  __attribute__((ext_vector_type(4)));
typedef char  char8v __attribute__((ext_vector_type(8)));

#define NROWS 8192
#define DIM 512
#define ROWB 512           // DIM * 1 byte (i8)
#define NT 4               // K-tiles of BK=128 i8

#define AS1(p) ((const __attribute__((address_space(1))) void*)(p))
#define AS3(p) ((__attribute__((address_space(3))) void*)(p))

#if __has_builtin(__builtin_amdgcn_exp2f)
#define EXP2(x) __builtin_amdgcn_exp2f(x)
#else
#define EXP2(x) exp2f(x)
#endif

// ---------------------------------------------------------------------------
// Kernel 1: wave-per-row normalize + i8 quantize + diag + rowsum zero.
// 64 lanes x 8 f32 = 512 elements; shuffle-only reduction (no LDS/barrier).
// ---------------------------------------------------------------------------
__global__ __launch_bounds__(256) void prep_kernel(
    const float* __restrict__ v, const float* __restrict__ u,
    char* __restrict__ vq, char* __restrict__ uq,
    float* __restrict__ sa, float* __restrict__ sb,
    float* __restrict__ diag, float* __restrict__ rowsum)
{
    const int row  = blockIdx.x * 4 + (threadIdx.x >> 6);
    const int lane = threadIdx.x & 63;
    const float4* vr = reinterpret_cast<const float4*>(v + (size_t)row * DIM);
    const float4* ur = reinterpret_cast<const float4*>(u + (size_t)row * DIM);
    const float4 a0 = vr[lane * 2], a1 = vr[lane * 2 + 1];
    const float4 b0 = ur[lane * 2], b1 = ur[lane * 2 + 1];
    float av[8] = {a0.x, a0.y, a0.z, a0.w, a1.x, a1.y, a1.z, a1.w};
    float bv[8] = {b0.x, b0.y, b0.z, b0.w, b1.x, b1.y, b1.z, b1.w};
    float sv = 0.f, su = 0.f, sd = 0.f, mv = 0.f, mu = 0.f;
#pragma unroll
    for (int i = 0; i < 8; ++i) {
        sv += av[i] * av[i];
        su += bv[i] * bv[i];
        sd += av[i] * bv[i];
        mv = fmaxf(mv, fabsf(av[i]));
        mu = fmaxf(mu, fabsf(bv[i]));
    }
#pragma unroll
    for (int m = 32; m; m >>= 1) {
        sv += __shfl_xor(sv, m);
        su += __shfl_xor(su, m);
        sd += __shfl_xor(sd, m);
        mv = fmaxf(mv, __shfl_xor(mv, m));
        mu = fmaxf(mu, __shfl_xor(mu, m));
    }
    const float rv = 1.0f / fmaxf(sqrtf(sv), 1e-8f);
    const float ru = 1.0f / fmaxf(sqrtf(su), 1e-8f);
    const float qv = 127.0f / fmaxf(mv, 1e-20f);
    const float qu = 127.0f / fmaxf(mu, 1e-20f);
    char8v cv, cu;
#pragma unroll
    for (int i = 0; i < 8; ++i) {
        cv[i] = (char)__float2int_rn(av[i] * qv);
        cu[i] = (char)__float2int_rn(bv[i] * qu);
    }
    reinterpret_cast<char8v*>(vq + (size_t)row * DIM)[lane] = cv;
    reinterpret_cast<char8v*>(uq + (size_t)row * DIM)[lane] = cu;
    if (lane == 0) {
        sa[row] = mv * rv / 127.0f;
        sb[row] = mu * ru / 127.0f;
        diag[row] = sd * rv * ru;
        rowsum[row] = 0.0f;
    }
}

// ---------------------------------------------------------------------------
// Kernel 2: A-stationary-in-registers i8 GEMM + fused exp2 rowsum.
// Grid 64 x 8: block = 128 rows (4 waves x 32 rows) sweeping 8 col-tiles of
// 128. A (128 x 512 i8) loaded ONCE to VGPRs (16 int4v/thread). B double-
// buffered in LDS (2 x 16 KB), 2-phase: stage(next) issued BEFORE compute,
// single __syncthreads per K-step (drains vmcnt+lgkmcnt). XOR-swizzled B
// (0-conflict, verified R5/R6). Row-partials accumulate in registers across
// the sweep; one atomicAdd per row per block at the end (64K total).
// ---------------------------------------------------------------------------
__global__ __launch_bounds__(256, 2) void simsum_kernel(
    const char* __restrict__ A, const char* __restrict__ Bm,
    const float* __restrict__ sa, const float* __restrict__ sb,
    float* __restrict__ rowsum)
{
    __shared__ __align__(16) char ldsB[2][16384];   // [buf][128 rows x 128 B]
    const int tid  = threadIdx.x;
    const int wave = tid >> 6;
    const int lane = tid & 63;
    const int ln15 = lane & 15;
    const int lhi  = lane >> 4;
    const int swz  = (ln15 & 7) << 4;          // read-side XOR (= row&7 <<4)

    const int brow = blockIdx.x;               // 0..63 -> 128 rows each
    const int bgrp = blockIdx.y;               // 0..7  -> sweeps 8 col-tiles
    const int growA = brow * 128 + wave * 32;  // this wave's 32 rows
    const int gcol0 = bgrp * 1024;             // this block's 1024 cols

    const char* gA = A;
    const char* gB = Bm;

    // ---- A into registers: [t][kk][m], 16 x int4v = 64 VGPR ----
    int4v Areg[NT][2][2];
#pragma unroll
    for (int t = 0; t < NT; ++t)
#pragma unroll
        for (int kk = 0; kk < 2; ++kk)
#pragma unroll
            for (int m = 0; m < 2; ++m) {
                const int r = growA + m * 16 + ln15;
                Areg[t][kk][m] = *reinterpret_cast<const int4v*>(
                    gA + (size_t)r * ROWB + t * 128 + kk * 64 + lhi * 16);
            }

    // per-row dequant scale (x 2*log2e) for this thread's 8 rows
    const float C2 = 2.885390081777927f;   // 2 * log2(e)
    float ga[2][4];
#pragma unroll
    for (int m = 0; m < 2; ++m)
#pragma unroll
        for (int rr = 0; rr < 4; ++rr)
            ga[m][rr] = sa[growA + m * 16 + lhi * 4 + rr] * C2;

    float rs[2][4];
#pragma unroll
    for (int m = 0; m < 2; ++m)
#pragma unroll
        for (int rr = 0; rr < 4; ++rr)
            rs[m][rr] = 0.f;

    // staging: 4 gloads/thread cover one 16 KB B tile; linear LDS dest,
    // source column chunk pre-swizzled (G21 both-sides pairing).
    const int r0   = tid >> 3;
    const int sl16 = (((tid & 7) ^ ((tid >> 3) & 7)) << 4);

    auto stageB = [&](int buf, int s, int t) {
#pragma unroll
        for (int g = 0; g < 4; ++g) {
            const int r = g * 32 + r0;                    // col-row in tile
            __builtin_amdgcn_global_load_lds(
                AS1(gB + (size_t)(gcol0 + s * 128 + r) * ROWB + t * 128 + sl16),
                AS3(&ldsB[buf][g * 4096 + tid * 16]), 16, 0, 0);
        }
    };

    stageB(0, 0, 0);
    __syncthreads();

    int buf = 0;
    for (int s = 0; s < 8; ++s) {
        int4v acc[2][8];
#pragma unroll
        for (int m = 0; m < 2; ++m)
#pragma unroll
            for (int n = 0; n < 8; ++n)
                acc[m][n] = (int4v){0, 0, 0, 0};

#pragma unroll
        for (int t = 0; t < NT; ++t) {
            const int nx = s * 4 + t + 1;          // next step in sweep
            if (nx < 32) stageB(buf ^ 1, nx >> 2, nx & 3);
#pragma unroll
            for (int kk = 0; kk < 2; ++kk) {
                int4v Bf[8];
#pragma unroll
                for (int n = 0; n < 8; ++n) {
                    const int r = n * 16 + ln15;
                    Bf[n] = *reinterpret_cast<const int4v*>(
                        &ldsB[buf][r * 128 + ((kk * 64 + lhi * 16) ^ swz)]);
                }
#pragma unroll
                for (int m = 0; m < 2; ++m)
#pragma unroll
                    for (int n = 0; n < 8; ++n)
                        acc[m][n] = __builtin_amdgcn_mfma_i32_16x16x64_i8(
                            Areg[t][kk][m], Bf[n], acc[m][n], 0, 0, 0);
            }
            __syncthreads();   // drains vmcnt (next tile staged) + lgkmcnt
            buf ^= 1;
        }

        // fused epilogue for this col-tile: lane-local partial row sums
        float sbv[8];
#pragma unroll
        for (int n = 0; n < 8; ++n)
            sbv[n] = sb[gcol0 + s * 128 + n * 16 + ln15];
#pragma unroll
        for (int m = 0; m < 2; ++m)
#pragma unroll
            for (int rr = 0; rr < 4; ++rr) {
                const float g = ga[m][rr];
#pragma unroll
                for (int n = 0; n < 8; ++n)
                    rs[m][rr] += EXP2((float)acc[m][n][rr] * g * sbv[n]);
            }
    }

    // final cross-lane reduce (cols live across ln15) + one atomic per row
#pragma unroll
    for (int m = 0; m < 2; ++m)
#pragma unroll
        for (int rr = 0; rr < 4; ++rr) {
            float s = rs[m][rr];
            s += __shfl_xor(s, 1);
            s += __shfl_xor(s, 2);
            s += __shfl_xor(s, 4);
            s += __shfl_xor(s, 8);
            if (ln15 == 0)
                atomicAdd(&rowsum[growA + m * 16 + lhi * 4 + rr], s);
        }
}

// ---------------------------------------------------------------------------
// Kernel 3: loss_i = log(exp(2*diag_i) + rowsum_i) - 2*diag_i
// ---------------------------------------------------------------------------
__global__ __launch_bounds__(256) void loss_kernel(
    const float* __restrict__ diag, const float* __restrict__ rowsum,
    float* __restrict__ out)
{
    const int i = blockIdx.x * 256 + threadIdx.x;
    const float d2 = diag[i] * 2.0f;
    out[i] = logf(expf(d2) + rowsum[i]) - d2;
}

extern "C" void kernel_launch(void* const* d_in, const int* in_sizes, int n_in,
                              void* d_out, int out_size, void* d_ws, size_t ws_size,
                              hipStream_t stream) {
    const float* v = (const float*)d_in[0];
    const float* u = (const float*)d_in[1];
    float* out = (float*)d_out;
    char* ws = (char*)d_ws;
    char*  vq     = ws;                                   // 4 MiB
    char*  uq     = ws + (size_t)4194304;                 // 4 MiB
    float* sa     = (float*)(ws + (size_t)8388608);       // 32 KiB
    float* sb     = (float*)(ws + (size_t)8388608 + 32768);
    float* diag   = (float*)(ws + (size_t)8388608 + 65536);
    float* rowsum = (float*)(ws + (size_t)8388608 + 98304);

    prep_kernel<<<NROWS / 4, 256, 0, stream>>>(v, u, vq, uq, sa, sb, diag, rowsum);
    dim3 grid(64, 8);
    simsum_kernel<<<grid, 256, 0, stream>>>(vq, uq, sa, sb, rowsum);
    loss_kernel<<<NROWS / 256, 256, 0, stream>>>(diag, rowsum, out);
}